// Round 1
// baseline (993.928 us; speedup 1.0000x reference)
//
#include <hip/hip_runtime.h>

#define TE 64          // edges per block
#define XSTRIDE 132    // 128 floats + 4 pad -> e-stride = 132 words = 4 (mod 32) banks, conflict-free
#define THREADS 256

__global__ __launch_bounds__(THREADS, 4)
void linkmlp_kernel(const float* __restrict__ emb,   // [N,128]
                    const int*   __restrict__ ei,    // [2,E] int32
                    const float* __restrict__ W1,    // [256,256]
                    const float* __restrict__ b1,    // [256]
                    const float* __restrict__ W2,    // [256]
                    const float* __restrict__ b2p,   // [1]
                    float*       __restrict__ out,   // [E]
                    int E)
{
    __shared__ float x_lds[TE * XSTRIDE];
    __shared__ float red[4][TE];
    __shared__ int   s_idx[2][TE];

    const int tid  = threadIdx.x;
    const int base = blockIdx.x * TE;
    const int je   = tid & 7;        // edge group: thread covers edges je + 8*i, i=0..7
    const int jc   = tid >> 3;       // col group 0..31
    const int c0   = jc * 8;         // 8 contiguous cols per thread

    // ---- load edge indices for this tile ----
    if (tid < TE) {
        int e = base + tid;
        s_idx[0][tid] = (e < E) ? ei[e] : 0;
    } else if (tid < 2 * TE) {
        int t = tid - TE;
        int e = base + t;
        s_idx[1][t] = (e < E) ? ei[E + e] : 0;
    }
    __syncthreads();

    float acc[8][8];
    #pragma unroll
    for (int i = 0; i < 8; ++i)
        #pragma unroll
        for (int j = 0; j < 8; ++j)
            acc[i][j] = 0.f;

    // ---- two K-halves: half 0 = emb[row] vs W1 rows 0..127, half 1 = emb[col] vs rows 128..255 ----
    for (int half = 0; half < 2; ++half) {
        // gather 64 x 128 floats into LDS, coalesced float4 (32 lanes cover one node row)
        const int* nodes = s_idx[half];
        #pragma unroll
        for (int q = 0; q < 8; ++q) {
            int f   = tid + THREADS * q;        // 0..2047
            int e   = f >> 5;                   // edge 0..63
            int seg = f & 31;                   // float4 segment 0..31
            const float4* src = (const float4*)(emb + nodes[e] * 128) + seg;
            *(float4*)(&x_lds[e * XSTRIDE + seg * 4]) = *src;
        }
        __syncthreads();

        const float* Wb = W1 + (half * 128) * 256;
        for (int k0 = 0; k0 < 128; k0 += 4) {
            // stage 4 W1 rows x 8 cols (L1/L2-resident, broadcast across je replicas)
            float4 wrow[4][2];
            #pragma unroll
            for (int r = 0; r < 4; ++r) {
                const float* wr = Wb + (k0 + r) * 256 + c0;
                wrow[r][0] = *(const float4*)(wr);
                wrow[r][1] = *(const float4*)(wr + 4);
            }
            #pragma unroll
            for (int i = 0; i < 8; ++i) {
                float4 xv = *(const float4*)(&x_lds[(je + 8 * i) * XSTRIDE + k0]);
                const float xk[4] = {xv.x, xv.y, xv.z, xv.w};
                #pragma unroll
                for (int r = 0; r < 4; ++r) {
                    const float4 wa = wrow[r][0];
                    const float4 wb = wrow[r][1];
                    acc[i][0] += xk[r] * wa.x;
                    acc[i][1] += xk[r] * wa.y;
                    acc[i][2] += xk[r] * wa.z;
                    acc[i][3] += xk[r] * wa.w;
                    acc[i][4] += xk[r] * wb.x;
                    acc[i][5] += xk[r] * wb.y;
                    acc[i][6] += xk[r] * wb.z;
                    acc[i][7] += xk[r] * wb.w;
                }
            }
        }
        __syncthreads();   // protect x_lds before next gather overwrites it
    }

    // ---- epilogue: bias + relu + dot W2, reduce over col groups ----
    float b1v[8], w2v[8];
    #pragma unroll
    for (int j = 0; j < 8; ++j) {
        b1v[j] = b1[c0 + j];
        w2v[j] = W2[c0 + j];
    }
    const int lane = tid & 63;
    const int wv   = tid >> 6;
    #pragma unroll
    for (int i = 0; i < 8; ++i) {
        float p = 0.f;
        #pragma unroll
        for (int j = 0; j < 8; ++j) {
            float h = acc[i][j] + b1v[j];
            p += (h > 0.f ? h : 0.f) * w2v[j];
        }
        // reduce across the 8 col-groups within the wave (lanes differing in bits 3..5)
        p += __shfl_xor(p, 8, 64);
        p += __shfl_xor(p, 16, 64);
        p += __shfl_xor(p, 32, 64);
        if ((lane >> 3) == 0)
            red[wv][je + 8 * i] = p;
    }
    __syncthreads();

    if (tid < TE) {
        int eg = base + tid;
        if (eg < E) {
            float raw = red[0][tid] + red[1][tid] + red[2][tid] + red[3][tid] + b2p[0];
            // w = relu(raw); w < T ? 0 : w  ==  raw < T ? 0 : raw   (T = 0.05 > 0)
            out[eg] = (raw < 0.05f) ? 0.f : raw;
        }
    }
}

extern "C" void kernel_launch(void* const* d_in, const int* in_sizes, int n_in,
                              void* d_out, int out_size, void* d_ws, size_t ws_size,
                              hipStream_t stream) {
    const float* emb = (const float*)d_in[0];
    const int*   ei  = (const int*)  d_in[1];
    const float* W1  = (const float*)d_in[2];
    const float* b1  = (const float*)d_in[3];
    const float* W2  = (const float*)d_in[4];
    const float* b2  = (const float*)d_in[5];
    float* out = (float*)d_out;

    const int E = out_size;                    // output is [E]
    const int grid = (E + TE - 1) / TE;        // 9375 for E=600000
    hipLaunchKernelGGL(linkmlp_kernel, dim3(grid), dim3(THREADS), 0, stream,
                       emb, ei, W1, b1, W2, b2, out, E);
}

// Round 2
// 953.638 us; speedup vs baseline: 1.0422x; 1.0422x over previous
//
#include <hip/hip_runtime.h>

#define TE 64          // edges per block
#define XSTRIDE 132    // 128 floats + 4 pad -> e-stride = 132 words = 4 (mod 32) banks, conflict-free
#define THREADS 256

// __launch_bounds__(256,3): cap = 512/3 = 170 VGPR/wave. R1's (256,4) forced a
// 64-VGPR allocation -> acc[8][8] spilled to scratch (WRITE_SIZE 218 MB/dispatch).
// Live set here is ~130 VGPR: acc 64 + W-rows 32 + x transients + addressing.
__global__ __launch_bounds__(THREADS, 3)
void linkmlp_kernel(const float* __restrict__ emb,   // [N,128]
                    const int*   __restrict__ ei,    // [2,E] int32
                    const float* __restrict__ W1,    // [256,256]
                    const float* __restrict__ b1,    // [256]
                    const float* __restrict__ W2,    // [256]
                    const float* __restrict__ b2p,   // [1]
                    float*       __restrict__ out,   // [E]
                    int E)
{
    __shared__ float x_lds[TE * XSTRIDE];
    __shared__ float red[4][TE];
    __shared__ int   s_idx[2][TE];

    const int tid  = threadIdx.x;
    const int base = blockIdx.x * TE;
    const int je   = tid & 7;        // edge group: thread covers edges je + 8*i, i=0..7
    const int jc   = tid >> 3;       // col group 0..31
    const int c0   = jc * 8;         // 8 contiguous cols per thread

    // ---- load edge indices for this tile ----
    if (tid < TE) {
        int e = base + tid;
        s_idx[0][tid] = (e < E) ? ei[e] : 0;
    } else if (tid < 2 * TE) {
        int t = tid - TE;
        int e = base + t;
        s_idx[1][t] = (e < E) ? ei[E + e] : 0;
    }
    __syncthreads();

    float acc[8][8];
    #pragma unroll
    for (int i = 0; i < 8; ++i)
        #pragma unroll
        for (int j = 0; j < 8; ++j)
            acc[i][j] = 0.f;

    // ---- two K-halves: half 0 = emb[row] vs W1 rows 0..127, half 1 = emb[col] vs rows 128..255 ----
    for (int half = 0; half < 2; ++half) {
        // gather 64 x 128 floats into LDS, coalesced float4 (32 lanes cover one node row)
        const int* nodes = s_idx[half];
        #pragma unroll
        for (int q = 0; q < 8; ++q) {
            int f   = tid + THREADS * q;        // 0..2047
            int e   = f >> 5;                   // edge 0..63
            int seg = f & 31;                   // float4 segment 0..31
            const float4* src = (const float4*)(emb + nodes[e] * 128) + seg;
            *(float4*)(&x_lds[e * XSTRIDE + seg * 4]) = *src;
        }
        __syncthreads();

        const float* Wb = W1 + (half * 128) * 256;
        for (int k0 = 0; k0 < 128; k0 += 4) {
            // stage 4 W1 rows x 8 cols (L2-resident, broadcast across je replicas)
            float4 wrow[4][2];
            #pragma unroll
            for (int r = 0; r < 4; ++r) {
                const float* wr = Wb + (k0 + r) * 256 + c0;
                wrow[r][0] = *(const float4*)(wr);
                wrow[r][1] = *(const float4*)(wr + 4);
            }
            #pragma unroll
            for (int i = 0; i < 8; ++i) {
                float4 xv = *(const float4*)(&x_lds[(je + 8 * i) * XSTRIDE + k0]);
                const float xk[4] = {xv.x, xv.y, xv.z, xv.w};
                #pragma unroll
                for (int r = 0; r < 4; ++r) {
                    const float4 wa = wrow[r][0];
                    const float4 wb = wrow[r][1];
                    acc[i][0] += xk[r] * wa.x;
                    acc[i][1] += xk[r] * wa.y;
                    acc[i][2] += xk[r] * wa.z;
                    acc[i][3] += xk[r] * wa.w;
                    acc[i][4] += xk[r] * wb.x;
                    acc[i][5] += xk[r] * wb.y;
                    acc[i][6] += xk[r] * wb.z;
                    acc[i][7] += xk[r] * wb.w;
                }
            }
        }
        __syncthreads();   // protect x_lds before next gather overwrites it
    }

    // ---- epilogue: bias + relu + dot W2, reduce over col groups ----
    float b1v[8], w2v[8];
    #pragma unroll
    for (int j = 0; j < 8; ++j) {
        b1v[j] = b1[c0 + j];
        w2v[j] = W2[c0 + j];
    }
    const int lane = tid & 63;
    const int wv   = tid >> 6;
    #pragma unroll
    for (int i = 0; i < 8; ++i) {
        float p = 0.f;
        #pragma unroll
        for (int j = 0; j < 8; ++j) {
            float h = acc[i][j] + b1v[j];
            p += (h > 0.f ? h : 0.f) * w2v[j];
        }
        // reduce across the 8 col-groups within the wave (lanes differing in bits 3..5)
        p += __shfl_xor(p, 8, 64);
        p += __shfl_xor(p, 16, 64);
        p += __shfl_xor(p, 32, 64);
        if ((lane >> 3) == 0)
            red[wv][je + 8 * i] = p;
    }
    __syncthreads();

    if (tid < TE) {
        int eg = base + tid;
        if (eg < E) {
            float raw = red[0][tid] + red[1][tid] + red[2][tid] + red[3][tid] + b2p[0];
            // w = relu(raw); w < T ? 0 : w  ==  raw < T ? 0 : raw   (T = 0.05 > 0)
            out[eg] = (raw < 0.05f) ? 0.f : raw;
        }
    }
}

extern "C" void kernel_launch(void* const* d_in, const int* in_sizes, int n_in,
                              void* d_out, int out_size, void* d_ws, size_t ws_size,
                              hipStream_t stream) {
    const float* emb = (const float*)d_in[0];
    const int*   ei  = (const int*)  d_in[1];
    const float* W1  = (const float*)d_in[2];
    const float* b1  = (const float*)d_in[3];
    const float* W2  = (const float*)d_in[4];
    const float* b2  = (const float*)d_in[5];
    float* out = (float*)d_out;

    const int E = out_size;                    // output is [E]
    const int grid = (E + TE - 1) / TE;        // 9375 for E=600000
    hipLaunchKernelGGL(linkmlp_kernel, dim3(grid), dim3(THREADS), 0, stream,
                       emb, ei, W1, b1, W2, b2, out, E);
}

// Round 3
// 527.996 us; speedup vs baseline: 1.8825x; 1.8061x over previous
//
#include <hip/hip_runtime.h>

#define TE 64
#define THREADS 256
#define T_SM 0.05f
#define NEAR_MARGIN 1e-3f

typedef short s8v __attribute__((ext_vector_type(8)));   // 8 bf16 (guide §3: frag_ab)
typedef float f4v __attribute__((ext_vector_type(4)));   // 4 fp32 (frag_cd)
typedef unsigned short u16;

__device__ __forceinline__ u16 f2bf(float x) {          // fp32 -> bf16 RNE
    union { float f; unsigned u; } v; v.f = x;
    return (u16)((v.u + 0x7FFFu + ((v.u >> 16) & 1u)) >> 16);
}
__device__ __forceinline__ float bf2f(u16 h) {
    union { unsigned u; float f; } v; v.u = ((unsigned)h) << 16;
    return v.f;
}

// ---- kernel 1: W1 [256,256] f32 -> w1t bf16 hi/lo in B-fragment layout ----
// layout: n in [0,256), k-group g=k/8 in [0,32): row = 512 ushort;
//   hi j=k&7 at n*512 + g*16 + j ; lo at +8  (so one lane's frag = 16B contiguous)
__global__ void prep_kernel(const float* __restrict__ W1, u16* __restrict__ w1t,
                            int* __restrict__ count) {
    int t = blockIdx.x * 256 + threadIdx.x;
    if (t == 0) *count = 0;
    if (t < 65536) {
        int n = t & 255, k = t >> 8;
        float w = W1[k * 256 + n];
        u16 h = f2bf(w);
        u16 l = f2bf(w - bf2f(h));
        int g = k >> 3, j = k & 7;
        w1t[n * 512 + g * 16 + j] = h;
        w1t[n * 512 + g * 16 + j + 8] = l;
    }
}

// ---- kernel 2: fused gather + split-bf16 MFMA GEMM + epilogue ----
// wave wv owns cols [wv*64, wv*64+64) x all 64 edges.
// A-frag layout (16x16x32): A[m=lane&15][k=(lane>>4)*8+j]; B[k][n=lane&15] mirrored.
// C/D: D[row=(lane>>4)*4+reg][col=lane&15]  (m89-verified).
__global__ __launch_bounds__(THREADS, 3)
void linkmlp_mfma(const float* __restrict__ emb, const int* __restrict__ ei,
                  const u16* __restrict__ w1t, const float* __restrict__ b1,
                  const float* __restrict__ W2, const float* __restrict__ b2p,
                  float* __restrict__ out, int* __restrict__ count,
                  int* __restrict__ list, int cap, int E)
{
    __shared__ u16 x_hi[TE * 136];   // 128 k + 8 pad per edge (272B row, 16B-aligned)
    __shared__ u16 x_lo[TE * 136];
    __shared__ float red[4][TE];
    __shared__ int s_idx[2][TE];

    const int tid  = threadIdx.x;
    const int base = blockIdx.x * TE;
    const int lane = tid & 63;
    const int wv   = tid >> 6;
    const int nn   = lane & 15;
    const int q    = lane >> 4;

    if (tid < TE) { int e = base + tid; s_idx[0][tid] = (e < E) ? ei[e] : 0; }
    else if (tid < 2 * TE) { int t2 = tid - TE; int e = base + t2; s_idx[1][t2] = (e < E) ? ei[E + e] : 0; }
    __syncthreads();

    f4v acc[4][4];
    #pragma unroll
    for (int mt = 0; mt < 4; ++mt)
        #pragma unroll
        for (int t = 0; t < 4; ++t)
            acc[mt][t] = (f4v)0.f;

    for (int half = 0; half < 2; ++half) {
        // gather 64 edges x 128 floats, split to bf16 hi/lo in LDS
        const int* nodes = s_idx[half];
        #pragma unroll
        for (int q2 = 0; q2 < 8; ++q2) {
            int f = tid + THREADS * q2;
            int e = f >> 5, seg = f & 31;
            const float4 v = ((const float4*)(emb + (size_t)nodes[e] * 128))[seg];
            u16 h0 = f2bf(v.x), h1 = f2bf(v.y), h2 = f2bf(v.z), h3 = f2bf(v.w);
            u16 l0 = f2bf(v.x - bf2f(h0)), l1 = f2bf(v.y - bf2f(h1));
            u16 l2 = f2bf(v.z - bf2f(h2)), l3 = f2bf(v.w - bf2f(h3));
            uint2 hp = make_uint2((unsigned)h0 | ((unsigned)h1 << 16), (unsigned)h2 | ((unsigned)h3 << 16));
            uint2 lp = make_uint2((unsigned)l0 | ((unsigned)l1 << 16), (unsigned)l2 | ((unsigned)l3 << 16));
            ((uint2*)x_hi)[e * 34 + seg] = hp;   // ds_write_b64
            ((uint2*)x_lo)[e * 34 + seg] = lp;
        }
        __syncthreads();

        #pragma unroll
        for (int s = 0; s < 4; ++s) {
            s8v ah[4], al[4];
            #pragma unroll
            for (int mt = 0; mt < 4; ++mt) {
                int off = (mt * 16 + nn) * 136 + 32 * s + 8 * q;
                ah[mt] = *(const s8v*)&x_hi[off];   // ds_read_b128
                al[mt] = *(const s8v*)&x_lo[off];
            }
            #pragma unroll
            for (int t = 0; t < 4; ++t) {
                const u16* bp = w1t + ((wv * 64 + t * 16 + nn) * 512 + (half * 16 + 4 * s + q) * 16);
                s8v bh = *(const s8v*)bp;           // global_load_dwordx4, L2-hot
                s8v bl = *(const s8v*)(bp + 8);
                #pragma unroll
                for (int mt = 0; mt < 4; ++mt) {    // 3-term split: xh*wh + xh*wl + xl*wh
                    acc[mt][t] = __builtin_amdgcn_mfma_f32_16x16x32_bf16(ah[mt], bh, acc[mt][t], 0, 0, 0);
                    acc[mt][t] = __builtin_amdgcn_mfma_f32_16x16x32_bf16(ah[mt], bl, acc[mt][t], 0, 0, 0);
                    acc[mt][t] = __builtin_amdgcn_mfma_f32_16x16x32_bf16(al[mt], bh, acc[mt][t], 0, 0, 0);
                }
            }
        }
        __syncthreads();   // protect x LDS before next half's gather
    }

    // epilogue: h = relu(acc + b1); partial = sum_n h*W2  (per wave: its 64 cols)
    float b1v[4], w2v[4];
    #pragma unroll
    for (int t = 0; t < 4; ++t) {
        int n = wv * 64 + t * 16 + nn;
        b1v[t] = b1[n];
        w2v[t] = W2[n];
    }
    #pragma unroll
    for (int mt = 0; mt < 4; ++mt) {
        #pragma unroll
        for (int r = 0; r < 4; ++r) {
            float p = 0.f;
            #pragma unroll
            for (int t = 0; t < 4; ++t) {
                float h = acc[mt][t][r] + b1v[t];
                p += (h > 0.f ? h : 0.f) * w2v[t];
            }
            p += __shfl_xor(p, 1);   // butterfly over nn (16-group)
            p += __shfl_xor(p, 2);
            p += __shfl_xor(p, 4);
            p += __shfl_xor(p, 8);
            if (nn == 0) red[wv][mt * 16 + q * 4 + r] = p;
        }
    }
    __syncthreads();

    if (tid < TE) {
        int eg = base + tid;
        if (eg < E) {
            float raw = red[0][tid] + red[1][tid] + red[2][tid] + red[3][tid] + b2p[0];
            out[eg] = (raw < T_SM) ? 0.f : raw;
            if (fabsf(raw - T_SM) < NEAR_MARGIN) {   // near-threshold: queue exact recompute
                int pos = atomicAdd(count, 1);
                if (pos < cap) list[pos] = eg;
            }
        }
    }
}

// ---- kernel 3: exact fp32 recompute of near-threshold edges (one wave/edge) ----
__global__ __launch_bounds__(256, 4)
void fixup_kernel(const float* __restrict__ emb, const int* __restrict__ ei,
                  const float* __restrict__ W1, const float* __restrict__ b1,
                  const float* __restrict__ W2, const float* __restrict__ b2p,
                  const int* __restrict__ count, const int* __restrict__ list,
                  float* __restrict__ out, int E, int cap)
{
    int cnt = *count; if (cnt > cap) cnt = cap;
    const int lane = threadIdx.x & 63;
    const int gw = (blockIdx.x * 256 + threadIdx.x) >> 6;
    const int nw = (gridDim.x * 256) >> 6;
    for (int i = gw; i < cnt; i += nw) {
        int e = list[i];
        int rn = ei[e], cn = ei[E + e];
        const float* src = (lane < 32) ? emb + (size_t)rn * 128 + lane * 4
                                       : emb + (size_t)cn * 128 + (lane - 32) * 4;
        float4 xv = *(const float4*)src;   // lane holds x[4*lane .. 4*lane+3]
        float hacc[4] = {0.f, 0.f, 0.f, 0.f};
        for (int k0 = 0; k0 < 256; k0 += 4) {
            int sl = k0 >> 2;
            float x0 = __shfl(xv.x, sl), x1 = __shfl(xv.y, sl);
            float x2 = __shfl(xv.z, sl), x3 = __shfl(xv.w, sl);
            #pragma unroll
            for (int c = 0; c < 4; ++c) {
                int col = lane + 64 * c;
                hacc[c] += x0 * W1[(k0 + 0) * 256 + col] + x1 * W1[(k0 + 1) * 256 + col]
                         + x2 * W1[(k0 + 2) * 256 + col] + x3 * W1[(k0 + 3) * 256 + col];
            }
        }
        float p = 0.f;
        #pragma unroll
        for (int c = 0; c < 4; ++c) {
            float h = hacc[c] + b1[lane + 64 * c];
            p += (h > 0.f ? h : 0.f) * W2[lane + 64 * c];
        }
        p += __shfl_xor(p, 1);  p += __shfl_xor(p, 2);  p += __shfl_xor(p, 4);
        p += __shfl_xor(p, 8);  p += __shfl_xor(p, 16); p += __shfl_xor(p, 32);
        if (lane == 0) {
            float raw = p + b2p[0];
            out[e] = (raw < T_SM) ? 0.f : raw;
        }
    }
}

extern "C" void kernel_launch(void* const* d_in, const int* in_sizes, int n_in,
                              void* d_out, int out_size, void* d_ws, size_t ws_size,
                              hipStream_t stream) {
    const float* emb = (const float*)d_in[0];
    const int*   ei  = (const int*)  d_in[1];
    const float* W1  = (const float*)d_in[2];
    const float* b1  = (const float*)d_in[3];
    const float* W2  = (const float*)d_in[4];
    const float* b2  = (const float*)d_in[5];
    float* out = (float*)d_out;
    const int E = out_size;

    // ws layout: [0,256KB) w1t bf16 hi/lo ; [256KB] count ; [256KB+64 ..) fixup list
    u16* w1t   = (u16*)d_ws;
    int* count = (int*)((char*)d_ws + 262144);
    int* list  = (int*)((char*)d_ws + 262208);
    long avail = (long)ws_size - 262208;
    int cap = (avail > 4) ? (int)(avail / 4) : 0;
    if (cap > E) cap = E;

    hipLaunchKernelGGL(prep_kernel, dim3(256), dim3(256), 0, stream, W1, w1t, count);
    hipLaunchKernelGGL(linkmlp_mfma, dim3((E + TE - 1) / TE), dim3(THREADS), 0, stream,
                       emb, ei, w1t, b1, W2, b2, out, count, list, cap, E);
    hipLaunchKernelGGL(fixup_kernel, dim3(128), dim3(256), 0, stream,
                       emb, ei, W1, b1, W2, b2, count, list, out, E, cap);
}